// Round 3
// baseline (841.420 us; speedup 1.0000x reference)
//
#include <hip/hip_runtime.h>
#include <hip/hip_bf16.h>

// Problem constants (AWQLinear): x[2,2048,4096] f32, q_weight[11008,4096] i32 in [0,16),
// scales[11008,128] f32, input_scale[4096] f32, bias[11008] f32 -> out[2,2048,11008] f32.
#define IN_F   4096
#define OUT_F  11008
#define MROWS  4096      // B*S
#define BK     64        // R2: K-tile doubled to amortize barrier drain (2 barriers / 32 MFMA)

typedef __attribute__((ext_vector_type(8))) short   bf16x8;  // 8 bf16 in 4 VGPRs
typedef __attribute__((ext_vector_type(8))) unsigned short ushortx8;
typedef __attribute__((ext_vector_type(4))) float   f32x4;

// fp32 -> bf16 round-to-nearest-even
static __device__ __forceinline__ unsigned short f2bf(float f) {
    unsigned int u = __builtin_bit_cast(unsigned int, f);
    u += 0x7fffu + ((u >> 16) & 1u);
    return (unsigned short)(u >> 16);
}

// async global->LDS, 16B per lane. HW dest = wave-uniform base + lane*16.
static __device__ __forceinline__ void gl_lds16(const void* g, void* l) {
    __builtin_amdgcn_global_load_lds((const __attribute__((address_space(1))) void*)g,
                                     (__attribute__((address_space(3))) void*)l,
                                     16, 0, 0);
}

// ---------------- kernel 1: W dequant (int4-as-int32 -> bf16), [OUT_F][IN_F] ----------------
__global__ __launch_bounds__(256) void dequant_w_kernel(const int* __restrict__ q,
                                                        const float* __restrict__ scales,
                                                        unsigned short* __restrict__ W) {
    const size_t base = ((size_t)blockIdx.x * 256 + threadIdx.x) * 8;   // 8 elems/thread
    const int4 q0 = *(const int4*)(q + base);
    const int4 q1 = *(const int4*)(q + base + 4);
    const int n = (int)(base >> 12);          // /IN_F
    const int k = (int)(base & (IN_F - 1));
    const float s = scales[(n << 7) | (k >> 5)];   // 8 consecutive k share one 32-block
    ushortx8 v;
    v[0] = f2bf(((float)q0.x - 8.0f) * s);
    v[1] = f2bf(((float)q0.y - 8.0f) * s);
    v[2] = f2bf(((float)q0.z - 8.0f) * s);
    v[3] = f2bf(((float)q0.w - 8.0f) * s);
    v[4] = f2bf(((float)q1.x - 8.0f) * s);
    v[5] = f2bf(((float)q1.y - 8.0f) * s);
    v[6] = f2bf(((float)q1.z - 8.0f) * s);
    v[7] = f2bf(((float)q1.w - 8.0f) * s);
    *(ushortx8*)(W + base) = v;
}

// ---------------- kernel 2: x / input_scale -> bf16, [MROWS][IN_F] ----------------
__global__ __launch_bounds__(256) void scale_x_kernel(const float* __restrict__ x,
                                                      const float* __restrict__ alpha,
                                                      unsigned short* __restrict__ Xs) {
    const size_t base = ((size_t)blockIdx.x * 256 + threadIdx.x) * 8;
    const int k = (int)(base & (IN_F - 1));
    const float4 x0 = *(const float4*)(x + base);
    const float4 x1 = *(const float4*)(x + base + 4);
    const float4 a0 = *(const float4*)(alpha + k);
    const float4 a1 = *(const float4*)(alpha + k + 4);
    ushortx8 v;
    v[0] = f2bf(x0.x / a0.x);
    v[1] = f2bf(x0.y / a0.y);
    v[2] = f2bf(x0.z / a0.z);
    v[3] = f2bf(x0.w / a0.w);
    v[4] = f2bf(x1.x / a1.x);
    v[5] = f2bf(x1.y / a1.y);
    v[6] = f2bf(x1.z / a1.z);
    v[7] = f2bf(x1.w / a1.w);
    *(ushortx8*)(Xs + base) = v;
}

// ---------------- kernel 3: C[M][N] = A[M][K] * W[N][K]^T + bias  ----------------
// 128x128 tile, BK=64, 256 thr = 4 waves, each wave 64x64 (4x4 tiles of 16x16x32 bf16 MFMA,
// 2 K-halves per LDS tile -> 32 MFMA per barrier pair).
// R1: 32Mx8N grid-group swizzle (L2/L3 locality) + LDS chunk-xor swizzle (0 bank conflicts).
// R2: BK 32 -> 64 to halve barrier-drain stalls per MFMA. LDS row = 64 bf16 = 128 B; swizzle
//     is now 8-wide: LDS(row, c) holds global(row, c ^ (row&7)).
__global__ __launch_bounds__(256) void gemm_bt_kernel(const unsigned short* __restrict__ A,
                                                      const unsigned short* __restrict__ Bw,
                                                      const float* __restrict__ bias,
                                                      float* __restrict__ C) {
    __shared__ __align__(16) unsigned short As[128 * BK];   // 16 KB
    __shared__ __align__(16) unsigned short Bs[128 * BK];   // 16 KB

    const int tid  = threadIdx.x;
    const int wave = tid >> 6;
    const int lane = tid & 63;

    // Grid swizzle: groups of 32 M-tiles x 8 N-tiles = 256 blocks.
    const int bid = blockIdx.x;
    int mtile, ntile;
    if (bid < 2560) {                       // 10 full groups of 8 N-tiles
        mtile = bid & 31;
        ntile = ((bid >> 8) << 3) + ((bid >> 5) & 7);
    } else {                                // remainder group: 6 N-tiles
        const int local = bid - 2560;
        mtile = local & 31;
        ntile = 80 + (local >> 5);
    }
    const int m0 = mtile << 7;
    const int n0 = ntile << 7;
    const int wm = (wave & 1) << 6;    // wave's 64-row quadrant
    const int wn = (wave >> 1) << 6;   // wave's 64-col quadrant

    // Staging: wave covers 32 rows (wave*32..+32) of each 128x64 tile, 4 chunks of 1024 B.
    // Chunk j fills 8 rows: row = wave*32 + j*8 + (lane>>3), col16 = lane&7.
    // Source swizzle: lane fetches global chunk (lane&7) ^ (row&7), row&7 = (lane>>3)&7.
    const int srow = wave * 32 + (lane >> 3);
    const int scol = (((lane & 7) ^ ((lane >> 3) & 7)) << 3);   // elements (8 bf16 = 16 B)
    const unsigned short* gA = A  + (size_t)(m0 + srow) * IN_F + scol;
    const unsigned short* gB = Bw + (size_t)(n0 + srow) * IN_F + scol;
    unsigned short* lA = As + wave * 2048 + lane * 8;    // wave base: 32 rows * 64 elem
    unsigned short* lB = Bs + wave * 2048 + lane * 8;

    f32x4 acc[4][4] = {};

    // MFMA fragment (16x16x32): m/n = lane&15, k = (lane>>4)*8 + j.
    // Read swizzle: global chunk g = (lane>>4) + h*4 lives at chunk g ^ (row&7), row&7 = lane&7.
    const int fr = lane & 15;
    const int q0c = lane >> 4;
    const int lx  = lane & 7;

    for (int kt = 0; kt < IN_F; kt += BK) {
        __syncthreads();                       // prior iter's ds_reads done before overwrite
#pragma unroll
        for (int j = 0; j < 4; ++j) {
            gl_lds16(gA + kt + (size_t)(j * 8) * IN_F, lA + j * 512);
            gl_lds16(gB + kt + (size_t)(j * 8) * IN_F, lB + j * 512);
        }
        __syncthreads();                       // drains vmcnt(0): staging visible

#pragma unroll
        for (int h = 0; h < 2; ++h) {          // two K=32 halves of the BK=64 tile
            const int cp = (((q0c + h * 4)) ^ lx) << 3;
            bf16x8 af[4], bfr[4];
#pragma unroll
            for (int mt = 0; mt < 4; ++mt)
                af[mt] = *(const bf16x8*)(As + (wm + mt * 16 + fr) * BK + cp);
#pragma unroll
            for (int nt = 0; nt < 4; ++nt)
                bfr[nt] = *(const bf16x8*)(Bs + (wn + nt * 16 + fr) * BK + cp);
#pragma unroll
            for (int mt = 0; mt < 4; ++mt)
#pragma unroll
                for (int nt = 0; nt < 4; ++nt)
                    acc[mt][nt] = __builtin_amdgcn_mfma_f32_16x16x32_bf16(af[mt], bfr[nt],
                                                                          acc[mt][nt], 0, 0, 0);
        }
    }

    // Epilogue: C/D layout col = lane&15, row = (lane>>4)*4 + reg. + bias.
    const int cr = (lane >> 4) << 2;
    const int cc = lane & 15;
#pragma unroll
    for (int nt = 0; nt < 4; ++nt) {
        const int gn = n0 + wn + nt * 16 + cc;
        const float bv = bias[gn];
#pragma unroll
        for (int mt = 0; mt < 4; ++mt) {
            const int gm = m0 + wm + mt * 16 + cr;
            float* cp = C + (size_t)gm * OUT_F + gn;
#pragma unroll
            for (int r = 0; r < 4; ++r)
                cp[(size_t)r * OUT_F] = acc[mt][nt][r] + bv;
        }
    }
}

extern "C" void kernel_launch(void* const* d_in, const int* in_sizes, int n_in,
                              void* d_out, int out_size, void* d_ws, size_t ws_size,
                              hipStream_t stream) {
    const float* x      = (const float*)d_in[0];
    const int*   qw     = (const int*)  d_in[1];
    const float* scales = (const float*)d_in[2];
    const float* alpha  = (const float*)d_in[3];
    const float* bias   = (const float*)d_in[4];
    float* out = (float*)d_out;

    // Workspace: W bf16 [OUT_F][IN_F] (~86 MiB) then Xs bf16 [MROWS][IN_F] (32 MiB).
    unsigned short* W  = (unsigned short*)d_ws;
    unsigned short* Xs = (unsigned short*)((char*)d_ws + (size_t)OUT_F * IN_F * 2);

    dequant_w_kernel<<<(OUT_F * IN_F) / (8 * 256), 256, 0, stream>>>(qw, scales, W);
    scale_x_kernel <<<(MROWS * IN_F) / (8 * 256), 256, 0, stream>>>(x, alpha, Xs);
    gemm_bt_kernel<<<(OUT_F / 128) * (MROWS / 128), 256, 0, stream>>>(Xs, W, bias, out);
}